// Round 2
// baseline (152.358 us; speedup 1.0000x reference)
//
#include <hip/hip_runtime.h>
#include <hip/hip_bf16.h>
#include <math.h>

#define NB 8
#define SQ 2048
#define EMB 256

typedef __attribute__((ext_vector_type(8))) short short8;
typedef __attribute__((ext_vector_type(4))) float f32x4;

__device__ __forceinline__ short f2bf(float f) {
    union { float f; unsigned u; } v; v.f = f;
    unsigned r = v.u + 0x7FFF + ((v.u >> 16) & 1);  // RNE
    return (short)(r >> 16);
}

// ---------------- K0: build WT bf16 [192][256]  (rows 0-63 Wq, 64-127 Wk, 128-191 Wv)
__global__ __launch_bounds__(256) void k_wt(const float* __restrict__ Wq,
                                            const float* __restrict__ Wk,
                                            const float* __restrict__ Wv,
                                            short* __restrict__ wt) {
    int o = blockIdx.x * 256 + threadIdx.x;   // < 192*256
    int row = o >> 8, e = o & 255;
    int w = row >> 6, d = row & 63;
    const float* W = (w == 0) ? Wq : ((w == 1) ? Wk : Wv);
    wt[o] = f2bf(W[e * 64 + d]);
}

// ---------------- K1: fused projection GEMM (obs fp32 read + inline bf16 cvt) -> q,k (scaled), vT
__global__ __launch_bounds__(256) void k_proj(const float* __restrict__ obs,
                                              const short* __restrict__ wt,
                                              short* __restrict__ qw,
                                              short* __restrict__ kw,
                                              short* __restrict__ vt) {
    int tid = threadIdx.x, w = tid >> 6, l = tid & 63;
    int rb = blockIdx.x;                 // 64 rows per block
    int r0 = rb * 64 + w * 16;
    int arow = r0 + (l & 15);
    int eo = (l >> 4) * 8;
    f32x4 acc[12];
    #pragma unroll
    for (int c = 0; c < 12; ++c) acc[c] = (f32x4){0.f, 0.f, 0.f, 0.f};
    #pragma unroll
    for (int ks = 0; ks < 8; ++ks) {
        int e0 = ks * 32;
        const float* ap = obs + (size_t)arow * 256 + e0 + eo;
        float4 f0 = *(const float4*)ap;
        float4 f1 = *(const float4*)(ap + 4);
        short8 a;
        a[0] = f2bf(f0.x); a[1] = f2bf(f0.y); a[2] = f2bf(f0.z); a[3] = f2bf(f0.w);
        a[4] = f2bf(f1.x); a[5] = f2bf(f1.y); a[6] = f2bf(f1.z); a[7] = f2bf(f1.w);
        #pragma unroll
        for (int c = 0; c < 12; ++c) {
            short8 bf = *(const short8*)(wt + (size_t)(c * 16 + (l & 15)) * 256 + e0 + eo);
            acc[c] = __builtin_amdgcn_mfma_f32_16x16x32_bf16(a, bf, acc[c], 0, 0, 0);
        }
    }
    const float scale = 0.35355339059327373f;  // 64^-0.25
    __shared__ short ldsv[64][72];
    int rloc = w * 16 + (l >> 4) * 4;
    int col16 = l & 15;
    #pragma unroll
    for (int c = 0; c < 12; ++c) {
        #pragma unroll
        for (int r = 0; r < 4; ++r) {
            float val = acc[c][r];
            int row = r0 + (l >> 4) * 4 + r;
            if (c < 4) {
                qw[(size_t)row * 64 + c * 16 + col16] = f2bf(val * scale);
            } else if (c < 8) {
                kw[(size_t)row * 64 + (c - 4) * 16 + col16] = f2bf(val * scale);
            } else {
                ldsv[(c - 8) * 16 + col16][rloc + r] = f2bf(val);
            }
        }
    }
    __syncthreads();
    int b = (rb * 64) >> 11;
    int s0 = (rb * 64) & 2047;
    int d = tid >> 2, ch = (tid & 3) * 16;
    short* dst = vt + (size_t)b * 64 * 2048 + (size_t)d * 2048 + s0 + ch;
    #pragma unroll
    for (int j = 0; j < 16; ++j) dst[j] = ldsv[d][ch + j];
}

// ---------------- K2: flash pass — online softmax + PV; writes ao and per-row (m, 1/l)
__global__ __launch_bounds__(256) void k_flash(const short* __restrict__ qw,
                                               const short* __restrict__ kw,
                                               const short* __restrict__ vt,
                                               float* __restrict__ ao,
                                               float* __restrict__ ml) {
    int qb = blockIdx.x, b = blockIdx.y;
    int q0 = qb * 64;
    int tid = threadIdx.x, w = tid >> 6, l = tid & 63;
    int lg = l >> 4, lc = l & 15;
    int r0 = q0 + w * 16;
    int eo = lg * 8;
    __shared__ short ldsP[4][16][72];   // 144B row pitch: 16B-aligned rows, near-conflict-free b128 reads
    const short* qbase = qw + (size_t)b * SQ * 64;
    const short* kbase = kw + (size_t)b * SQ * 64;
    const short* vbase = vt + (size_t)b * 64 * SQ;
    short8 qf0 = *(const short8*)(qbase + (size_t)(r0 + lc) * 64 + eo);
    short8 qf1 = *(const short8*)(qbase + (size_t)(r0 + lc) * 64 + 32 + eo);
    float m[4], lsum[4];
    f32x4 o[4];
    #pragma unroll
    for (int r = 0; r < 4; ++r) { m[r] = -INFINITY; lsum[r] = 0.f; }
    #pragma unroll
    for (int nj = 0; nj < 4; ++nj) o[nj] = (f32x4){0.f, 0.f, 0.f, 0.f};

    for (int kb = 0; kb <= qb; ++kb) {
        int k0 = kb * 64;
        f32x4 s[4];
        #pragma unroll
        for (int nj = 0; nj < 4; ++nj) s[nj] = (f32x4){0.f, 0.f, 0.f, 0.f};
        #pragma unroll
        for (int nj = 0; nj < 4; ++nj) {
            short8 kf = *(const short8*)(kbase + (size_t)(k0 + nj * 16 + lc) * 64 + eo);
            s[nj] = __builtin_amdgcn_mfma_f32_16x16x32_bf16(qf0, kf, s[nj], 0, 0, 0);
        }
        #pragma unroll
        for (int nj = 0; nj < 4; ++nj) {
            short8 kf = *(const short8*)(kbase + (size_t)(k0 + nj * 16 + lc) * 64 + 32 + eo);
            s[nj] = __builtin_amdgcn_mfma_f32_16x16x32_bf16(qf1, kf, s[nj], 0, 0, 0);
        }
        if (kb == qb) {
            #pragma unroll
            for (int nj = 0; nj < 4; ++nj)
                #pragma unroll
                for (int r = 0; r < 4; ++r)
                    if (k0 + nj * 16 + lc > r0 + lg * 4 + r) s[nj][r] = -INFINITY;
        }
        #pragma unroll
        for (int r = 0; r < 4; ++r) {
            float pm = fmaxf(fmaxf(s[0][r], s[1][r]), fmaxf(s[2][r], s[3][r]));
            pm = fmaxf(pm, __shfl_xor(pm, 1));
            pm = fmaxf(pm, __shfl_xor(pm, 2));
            pm = fmaxf(pm, __shfl_xor(pm, 4));
            pm = fmaxf(pm, __shfl_xor(pm, 8));
            float mn = fmaxf(m[r], pm);
            float sc = __expf(m[r] - mn);   // first tile: exp(-inf)=0
            m[r] = mn;
            lsum[r] *= sc;
            #pragma unroll
            for (int nj = 0; nj < 4; ++nj) o[nj][r] *= sc;
            float ps = 0.f;
            #pragma unroll
            for (int nj = 0; nj < 4; ++nj) {
                float p = __expf(s[nj][r] - mn);
                ps += p;
                ldsP[w][lg * 4 + r][nj * 16 + lc] = f2bf(p);
            }
            ps += __shfl_xor(ps, 1);
            ps += __shfl_xor(ps, 2);
            ps += __shfl_xor(ps, 4);
            ps += __shfl_xor(ps, 8);
            lsum[r] += ps;
        }
        // PV: wave-local LDS round-trip (in-order DS, no barrier needed)
        #pragma unroll
        for (int ks = 0; ks < 2; ++ks) {
            short8 pa = *(const short8*)&ldsP[w][lc][ks * 32 + lg * 8];
            #pragma unroll
            for (int nj = 0; nj < 4; ++nj) {
                short8 vf = *(const short8*)(vbase + (size_t)(nj * 16 + lc) * SQ + k0 + ks * 32 + eo);
                o[nj] = __builtin_amdgcn_mfma_f32_16x16x32_bf16(pa, vf, o[nj], 0, 0, 0);
            }
        }
    }
    #pragma unroll
    for (int r = 0; r < 4; ++r) {
        float inv = 1.f / lsum[r];
        int row = r0 + lg * 4 + r;
        if (lc == 0) {
            ml[((size_t)b * SQ + row) * 2]     = m[r];
            ml[((size_t)b * SQ + row) * 2 + 1] = inv;
        }
        #pragma unroll
        for (int nj = 0; nj < 4; ++nj)
            ao[((size_t)b * SQ + row) * 64 + nj * 16 + lc] = o[nj][r] * inv;
    }
}

// ---------------- K3: attn writer — recompute S (bit-identical), write exp(S-m)*invl; zeros above diag
__global__ __launch_bounds__(256) void k_attnw(const short* __restrict__ qw,
                                               const short* __restrict__ kw,
                                               const float* __restrict__ ml,
                                               float* __restrict__ attn) {
    int kb = blockIdx.x, qb = blockIdx.y, b = blockIdx.z;
    int q0 = qb * 64, k0 = kb * 64;
    float* abase = attn + (size_t)b * SQ * SQ;
    int tid = threadIdx.x;
    if (kb > qb) {   // strictly-upper tile: pure zero-fill, fully coalesced
        int row = q0 + (tid >> 2);
        float4* dst = (float4*)(abase + (size_t)row * SQ + k0 + (tid & 3) * 16);
        float4 z = {0.f, 0.f, 0.f, 0.f};
        dst[0] = z; dst[1] = z; dst[2] = z; dst[3] = z;
        return;
    }
    int w = tid >> 6, l = tid & 63, lg = l >> 4, lc = l & 15;
    int r0 = q0 + w * 16, eo = lg * 8;
    const short* qbase = qw + (size_t)b * SQ * 64;
    const short* kbase = kw + (size_t)b * SQ * 64;
    short8 qf0 = *(const short8*)(qbase + (size_t)(r0 + lc) * 64 + eo);
    short8 qf1 = *(const short8*)(qbase + (size_t)(r0 + lc) * 64 + 32 + eo);
    f32x4 s[4];
    #pragma unroll
    for (int nj = 0; nj < 4; ++nj) s[nj] = (f32x4){0.f, 0.f, 0.f, 0.f};
    #pragma unroll
    for (int nj = 0; nj < 4; ++nj) {
        short8 kf = *(const short8*)(kbase + (size_t)(k0 + nj * 16 + lc) * 64 + eo);
        s[nj] = __builtin_amdgcn_mfma_f32_16x16x32_bf16(qf0, kf, s[nj], 0, 0, 0);
    }
    #pragma unroll
    for (int nj = 0; nj < 4; ++nj) {
        short8 kf = *(const short8*)(kbase + (size_t)(k0 + nj * 16 + lc) * 64 + 32 + eo);
        s[nj] = __builtin_amdgcn_mfma_f32_16x16x32_bf16(qf1, kf, s[nj], 0, 0, 0);
    }
    #pragma unroll
    for (int r = 0; r < 4; ++r) {
        int row = r0 + lg * 4 + r;
        float mr = ml[((size_t)b * SQ + row) * 2];
        float iv = ml[((size_t)b * SQ + row) * 2 + 1];
        #pragma unroll
        for (int nj = 0; nj < 4; ++nj) {
            int col = k0 + nj * 16 + lc;
            float p = (col <= row) ? __expf(s[nj][r] - mr) * iv : 0.f;
            abase[(size_t)row * SQ + col] = p;
        }
    }
}

// ---------------- K4: MLP  x = relu(ao@W1+b1)@W2+b2
__global__ __launch_bounds__(256) void k_mlp(const float* __restrict__ ao,
                                             const float* __restrict__ W1,
                                             const float* __restrict__ b1,
                                             const float* __restrict__ W2,
                                             const float* __restrict__ b2,
                                             float* __restrict__ x) {
    int tid = threadIdx.x, w = tid >> 6, l = tid & 63;
    int grow = blockIdx.x * 4 + w;
    __shared__ float lds[4][64];
    lds[w][l] = ao[(size_t)grow * 64 + l];
    __syncthreads();
    float acc = b1[l];
    #pragma unroll
    for (int d = 0; d < 64; ++d) acc += lds[w][d] * W1[d * 64 + l];
    float h = fmaxf(acc, 0.f);
    float p = h * W2[l];
    #pragma unroll
    for (int o = 32; o > 0; o >>= 1) p += __shfl_xor(p, o);
    if (l == 0) x[grow] = p + b2[0];
}

extern "C" void kernel_launch(void* const* d_in, const int* in_sizes, int n_in,
                              void* d_out, int out_size, void* d_ws, size_t ws_size,
                              hipStream_t stream) {
    const float* obs = (const float*)d_in[0];
    const float* Wq  = (const float*)d_in[2];
    const float* Wk  = (const float*)d_in[3];
    const float* Wv  = (const float*)d_in[4];
    const float* W1  = (const float*)d_in[5];
    const float* b1  = (const float*)d_in[6];
    const float* W2  = (const float*)d_in[7];
    const float* b2  = (const float*)d_in[8];

    float* x    = (float*)d_out;                    // [16384]
    float* attn = (float*)d_out + NB * SQ;          // [8][2048][2048]

    char* ws = (char*)d_ws;
    short* wt = (short*)(ws);                       // 192*256 bf16
    short* qw = (short*)(ws + 131072);              // 16384*64 bf16
    short* kw = (short*)(ws + 2228224);             // 16384*64 bf16
    short* vt = (short*)(ws + 4325376);             // 8*64*2048 bf16
    float* ml = (float*)(ws + 6422528);             // 16384*2 f32 (m, 1/l)
    float* ao = (float*)(ws + 6553600);             // 16384*64 f32

    k_wt<<<dim3(192), dim3(256), 0, stream>>>(Wq, Wk, Wv, wt);
    k_proj<<<dim3(256), dim3(256), 0, stream>>>(obs, wt, qw, kw, vt);
    k_flash<<<dim3(32, NB), dim3(256), 0, stream>>>(qw, kw, vt, ao, ml);
    k_attnw<<<dim3(32, 32, NB), dim3(256), 0, stream>>>(qw, kw, ml, attn);
    k_mlp<<<dim3(4096), dim3(256), 0, stream>>>(ao, W1, b1, W2, b2, x);
}

// Round 3
// 136.856 us; speedup vs baseline: 1.1133x; 1.1133x over previous
//
#include <hip/hip_runtime.h>
#include <hip/hip_bf16.h>
#include <math.h>

#define NB 8
#define SQ 2048
#define QR 32     // q rows per fused block
#define NW 8      // waves per fused block

typedef __attribute__((ext_vector_type(8))) short short8;
typedef __attribute__((ext_vector_type(4))) float f32x4;

__device__ __forceinline__ short f2bf(float f) {
    union { float f; unsigned u; } v; v.f = f;
    unsigned r = v.u + 0x7FFF + ((v.u >> 16) & 1);  // RNE
    return (short)(r >> 16);
}

// ---------------- K0: build WT bf16 [192][256]  (rows 0-63 Wq, 64-127 Wk, 128-191 Wv)
__global__ __launch_bounds__(256) void k_wt(const float* __restrict__ Wq,
                                            const float* __restrict__ Wk,
                                            const float* __restrict__ Wv,
                                            short* __restrict__ wt) {
    int o = blockIdx.x * 256 + threadIdx.x;   // < 192*256
    int row = o >> 8, e = o & 255;
    int w = row >> 6, d = row & 63;
    const float* W = (w == 0) ? Wq : ((w == 1) ? Wk : Wv);
    wt[o] = f2bf(W[e * 64 + d]);
}

// ---------------- K1: projection GEMM, 16 rows/block, waves split cols {q,k,v}
__global__ __launch_bounds__(256, 4) void k_proj(const float* __restrict__ obs,
                                                 const short* __restrict__ wt,
                                                 short* __restrict__ qw,
                                                 short* __restrict__ kw,
                                                 short* __restrict__ vt) {
    int tid = threadIdx.x, w = tid >> 6, l = tid & 63, lg = l >> 4, lc = l & 15;
    int r0 = blockIdx.x * 16;
    int arow = r0 + lc;
    f32x4 accq = {0.f,0.f,0.f,0.f}, acck = {0.f,0.f,0.f,0.f}, accv = {0.f,0.f,0.f,0.f};
    const short* wq = wt + (size_t)(w * 16 + lc) * 256;
    const short* wk = wt + (size_t)(64 + w * 16 + lc) * 256;
    const short* wv = wt + (size_t)(128 + w * 16 + lc) * 256;
    #pragma unroll
    for (int ks = 0; ks < 8; ++ks) {
        int e0 = ks * 32 + lg * 8;
        const float* ap = obs + (size_t)arow * 256 + e0;
        float4 f0 = *(const float4*)ap;
        float4 f1 = *(const float4*)(ap + 4);
        short8 a;
        a[0] = f2bf(f0.x); a[1] = f2bf(f0.y); a[2] = f2bf(f0.z); a[3] = f2bf(f0.w);
        a[4] = f2bf(f1.x); a[5] = f2bf(f1.y); a[6] = f2bf(f1.z); a[7] = f2bf(f1.w);
        accq = __builtin_amdgcn_mfma_f32_16x16x32_bf16(a, *(const short8*)(wq + e0), accq, 0, 0, 0);
        acck = __builtin_amdgcn_mfma_f32_16x16x32_bf16(a, *(const short8*)(wk + e0), acck, 0, 0, 0);
        accv = __builtin_amdgcn_mfma_f32_16x16x32_bf16(a, *(const short8*)(wv + e0), accv, 0, 0, 0);
    }
    const float scale = 0.35355339059327373f;  // 64^-0.25
    __shared__ short ldsv[64][18];
    #pragma unroll
    for (int r = 0; r < 4; ++r) {
        int row = r0 + lg * 4 + r;
        qw[(size_t)row * 64 + w * 16 + lc] = f2bf(accq[r] * scale);
        kw[(size_t)row * 64 + w * 16 + lc] = f2bf(acck[r] * scale);
        ldsv[w * 16 + lc][lg * 4 + r] = f2bf(accv[r]);
    }
    __syncthreads();
    int b = r0 >> 11, s0 = r0 & 2047;
    int d = tid >> 2, sc = (tid & 3) * 4;
    short* dst = vt + (size_t)b * 64 * SQ + (size_t)d * SQ + s0 + sc;
    dst[0] = ldsv[d][sc]; dst[1] = ldsv[d][sc + 1];
    dst[2] = ldsv[d][sc + 2]; dst[3] = ldsv[d][sc + 3];
}

// ---------------- K2: fused flash (kv-split across 8 waves) + MLP + attn writer
__global__ __launch_bounds__(512, 2) void k_fused(const short* __restrict__ qw,
                                                  const short* __restrict__ kw,
                                                  const short* __restrict__ vt,
                                                  const float* __restrict__ W1,
                                                  const float* __restrict__ b1,
                                                  const float* __restrict__ W2,
                                                  const float* __restrict__ b2,
                                                  float* __restrict__ x,
                                                  float* __restrict__ attn) {
    int bx = blockIdx.x;
    int sq = 63 - (bx >> 3);        // longest strips first
    int b  = bx & 7;
    int s0 = sq * QR;
    int tid = threadIdx.x, w = tid >> 6, l = tid & 63, lg = l >> 4, lc = l & 15;
    int kbmax = sq >> 1;            // last (diagonal) kv tile index

    __shared__ short ldsP[NW][QR][72];
    __shared__ float o_acc[QR][72];
    __shared__ float mw[NW][QR], lw[NW][QR];
    __shared__ float mfin[QR], linv[QR];

    const short* qbase = qw + (size_t)b * SQ * 64;
    const short* kbase = kw + (size_t)b * SQ * 64;
    const short* vbase = vt + (size_t)b * 64 * SQ;

    short8 qf[2][2];
    #pragma unroll
    for (int mi = 0; mi < 2; ++mi)
        #pragma unroll
        for (int ks = 0; ks < 2; ++ks)
            qf[mi][ks] = *(const short8*)(qbase + (size_t)(s0 + mi * 16 + lc) * 64 + ks * 32 + lg * 8);

    f32x4 o[2][4];
    float m[8], ls[8];
    #pragma unroll
    for (int i = 0; i < 8; ++i) { m[i] = -INFINITY; ls[i] = 0.f; }
    #pragma unroll
    for (int mi = 0; mi < 2; ++mi)
        #pragma unroll
        for (int nj = 0; nj < 4; ++nj) o[mi][nj] = (f32x4){0.f,0.f,0.f,0.f};

    // ---- phase 1: online softmax + PV over this wave's kv tiles
    for (int kb = w; kb <= kbmax; kb += NW) {
        int k0 = kb * 64;
        f32x4 s[2][4];
        #pragma unroll
        for (int mi = 0; mi < 2; ++mi)
            #pragma unroll
            for (int nj = 0; nj < 4; ++nj) s[mi][nj] = (f32x4){0.f,0.f,0.f,0.f};
        #pragma unroll
        for (int nj = 0; nj < 4; ++nj) {
            short8 kf0 = *(const short8*)(kbase + (size_t)(k0 + nj * 16 + lc) * 64 + lg * 8);
            short8 kf1 = *(const short8*)(kbase + (size_t)(k0 + nj * 16 + lc) * 64 + 32 + lg * 8);
            #pragma unroll
            for (int mi = 0; mi < 2; ++mi) {
                s[mi][nj] = __builtin_amdgcn_mfma_f32_16x16x32_bf16(qf[mi][0], kf0, s[mi][nj], 0, 0, 0);
                s[mi][nj] = __builtin_amdgcn_mfma_f32_16x16x32_bf16(qf[mi][1], kf1, s[mi][nj], 0, 0, 0);
            }
        }
        if (kb == kbmax) {
            #pragma unroll
            for (int mi = 0; mi < 2; ++mi)
                #pragma unroll
                for (int nj = 0; nj < 4; ++nj)
                    #pragma unroll
                    for (int r = 0; r < 4; ++r)
                        if (k0 + nj * 16 + lc > s0 + mi * 16 + lg * 4 + r) s[mi][nj][r] = -INFINITY;
        }
        #pragma unroll
        for (int mi = 0; mi < 2; ++mi)
            #pragma unroll
            for (int r = 0; r < 4; ++r) {
                int ri = mi * 4 + r;
                int rowloc = mi * 16 + lg * 4 + r;
                float pm = fmaxf(fmaxf(s[mi][0][r], s[mi][1][r]), fmaxf(s[mi][2][r], s[mi][3][r]));
                pm = fmaxf(pm, __shfl_xor(pm, 1));
                pm = fmaxf(pm, __shfl_xor(pm, 2));
                pm = fmaxf(pm, __shfl_xor(pm, 4));
                pm = fmaxf(pm, __shfl_xor(pm, 8));
                float mn = fmaxf(m[ri], pm);
                float sc = __expf(m[ri] - mn);
                m[ri] = mn;
                ls[ri] *= sc;
                #pragma unroll
                for (int nj = 0; nj < 4; ++nj) o[mi][nj][r] *= sc;
                float ps = 0.f;
                #pragma unroll
                for (int nj = 0; nj < 4; ++nj) {
                    float p = __expf(s[mi][nj][r] - mn);
                    ps += p;
                    ldsP[w][rowloc][nj * 16 + lc] = f2bf(p);
                }
                ps += __shfl_xor(ps, 1);
                ps += __shfl_xor(ps, 2);
                ps += __shfl_xor(ps, 4);
                ps += __shfl_xor(ps, 8);
                ls[ri] += ps;
            }
        #pragma unroll
        for (int ks = 0; ks < 2; ++ks) {
            short8 pa0 = *(const short8*)&ldsP[w][lc][ks * 32 + lg * 8];
            short8 pa1 = *(const short8*)&ldsP[w][16 + lc][ks * 32 + lg * 8];
            #pragma unroll
            for (int nj = 0; nj < 4; ++nj) {
                short8 vf = *(const short8*)(vbase + (size_t)(nj * 16 + lc) * SQ + k0 + ks * 32 + lg * 8);
                o[0][nj] = __builtin_amdgcn_mfma_f32_16x16x32_bf16(pa0, vf, o[0][nj], 0, 0, 0);
                o[1][nj] = __builtin_amdgcn_mfma_f32_16x16x32_bf16(pa1, vf, o[1][nj], 0, 0, 0);
            }
        }
    }

    // ---- combine partials across waves
    #pragma unroll
    for (int mi = 0; mi < 2; ++mi)
        #pragma unroll
        for (int r = 0; r < 4; ++r) {
            int rowloc = mi * 16 + lg * 4 + r;
            if (lc == 0) { mw[w][rowloc] = m[mi * 4 + r]; lw[w][rowloc] = ls[mi * 4 + r]; }
        }
    for (int idx = tid; idx < QR * 72; idx += 512) ((float*)o_acc)[idx] = 0.f;
    __syncthreads();
    #pragma unroll
    for (int mi = 0; mi < 2; ++mi)
        #pragma unroll
        for (int r = 0; r < 4; ++r) {
            int rowloc = mi * 16 + lg * 4 + r;
            float mf = mw[0][rowloc];
            #pragma unroll
            for (int ww = 1; ww < NW; ++ww) mf = fmaxf(mf, mw[ww][rowloc]);
            float f = __expf(m[mi * 4 + r] - mf);
            #pragma unroll
            for (int nj = 0; nj < 4; ++nj)
                atomicAdd(&o_acc[rowloc][nj * 16 + lc], o[mi][nj][r] * f);
        }
    __syncthreads();

    // ---- fused MLP on combined rows (wave w owns rows 4w..4w+3); publish mfin/linv
    #pragma unroll
    for (int rr = 0; rr < 4; ++rr) {
        int rowloc = w * 4 + rr;
        float mf = mw[0][rowloc];
        #pragma unroll
        for (int ww = 1; ww < NW; ++ww) mf = fmaxf(mf, mw[ww][rowloc]);
        float lf = 0.f;
        #pragma unroll
        for (int ww = 0; ww < NW; ++ww) lf += __expf(mw[ww][rowloc] - mf) * lw[ww][rowloc];
        float inv = 1.f / lf;
        if (l == 0) { mfin[rowloc] = mf; linv[rowloc] = inv; }
        float t = 0.f;
        #pragma unroll 8
        for (int d = 0; d < 64; ++d) t += o_acc[rowloc][d] * W1[d * 64 + l];
        float h = fmaxf(t * inv + b1[l], 0.f);
        float px = h * W2[l];
        px += __shfl_xor(px, 1);
        px += __shfl_xor(px, 2);
        px += __shfl_xor(px, 4);
        px += __shfl_xor(px, 8);
        px += __shfl_xor(px, 16);
        px += __shfl_xor(px, 32);
        if (l == 0) x[(size_t)b * SQ + s0 + rowloc] = px + b2[0];
    }
    __syncthreads();

    // ---- phase 2: recompute S and stream normalized attn (+ zero fill)
    float* abase = attn + (size_t)b * SQ * SQ;
    for (int kb = w; kb < 32; kb += NW) {
        int k0 = kb * 64;
        if (kb > kbmax) {
            float4 z = {0.f,0.f,0.f,0.f};
            #pragma unroll
            for (int rep = 0; rep < 8; ++rep) {
                int row = s0 + rep * 4 + lg;
                *(float4*)(abase + (size_t)row * SQ + k0 + lc * 4) = z;
            }
            continue;
        }
        f32x4 s[2][4];
        #pragma unroll
        for (int mi = 0; mi < 2; ++mi)
            #pragma unroll
            for (int nj = 0; nj < 4; ++nj) s[mi][nj] = (f32x4){0.f,0.f,0.f,0.f};
        #pragma unroll
        for (int nj = 0; nj < 4; ++nj) {
            short8 kf0 = *(const short8*)(kbase + (size_t)(k0 + nj * 16 + lc) * 64 + lg * 8);
            short8 kf1 = *(const short8*)(kbase + (size_t)(k0 + nj * 16 + lc) * 64 + 32 + lg * 8);
            #pragma unroll
            for (int mi = 0; mi < 2; ++mi) {
                s[mi][nj] = __builtin_amdgcn_mfma_f32_16x16x32_bf16(qf[mi][0], kf0, s[mi][nj], 0, 0, 0);
                s[mi][nj] = __builtin_amdgcn_mfma_f32_16x16x32_bf16(qf[mi][1], kf1, s[mi][nj], 0, 0, 0);
            }
        }
        #pragma unroll
        for (int mi = 0; mi < 2; ++mi)
            #pragma unroll
            for (int r = 0; r < 4; ++r) {
                int rowloc = mi * 16 + lg * 4 + r;
                int row = s0 + rowloc;
                float mf = mfin[rowloc], iv = linv[rowloc];
                #pragma unroll
                for (int nj = 0; nj < 4; ++nj) {
                    int col = k0 + nj * 16 + lc;
                    float p = (col <= row) ? __expf(s[mi][nj][r] - mf) * iv : 0.f;
                    abase[(size_t)row * SQ + col] = p;
                }
            }
    }
}

extern "C" void kernel_launch(void* const* d_in, const int* in_sizes, int n_in,
                              void* d_out, int out_size, void* d_ws, size_t ws_size,
                              hipStream_t stream) {
    const float* obs = (const float*)d_in[0];
    const float* Wq  = (const float*)d_in[2];
    const float* Wk  = (const float*)d_in[3];
    const float* Wv  = (const float*)d_in[4];
    const float* W1  = (const float*)d_in[5];
    const float* b1  = (const float*)d_in[6];
    const float* W2  = (const float*)d_in[7];
    const float* b2  = (const float*)d_in[8];

    float* x    = (float*)d_out;                    // [16384]
    float* attn = (float*)d_out + NB * SQ;          // [8][2048][2048]

    char* ws = (char*)d_ws;
    short* wt = (short*)(ws);                       // 192*256 bf16
    short* qw = (short*)(ws + 131072);              // 16384*64 bf16
    short* kw = (short*)(ws + 2228224);             // 16384*64 bf16
    short* vt = (short*)(ws + 4325376);             // 8*64*2048 bf16

    k_wt<<<dim3(192), dim3(256), 0, stream>>>(Wq, Wk, Wv, wt);
    k_proj<<<dim3(1024), dim3(256), 0, stream>>>(obs, wt, qw, kw, vt);
    k_fused<<<dim3(512), dim3(512), 0, stream>>>(qw, kw, vt, W1, b1, W2, b2, x, attn);
}